// Round 11
// baseline (182.388 us; speedup 1.0000x reference)
//
#include <hip/hip_runtime.h>
#include <stdint.h>

// CriticNetwork, single self-contained kernel (R11):
//   value[b,i,m] = ve[i] + (sv[i] + w[i,m]*dv[m])/64
//   weights5[b,i,m,j] = w[b,i,j]   (broadcast over m)
// w = sigmoid(K Q^T / sqrt(128)); K/Q = oa @ Wk^T / Wq^T (bf16 MFMA, K-dim
// 144 zero-padded to 160); u = Wv^T wf2; g = Wenc^T wf1; vas=oa.u;
// dv=(pol-act).u[128:]; ve=obs.g; sv=w.vas.
// R10 ledger: every multi-kernel variant leaves ~55us unexplained and our
// kernels never crack top-5 (fills 79-85us censor them). This round: ONE
// dispatch per launch; broadcast = hoisted LDS reads + pure store burst.
// Either dur drops to ~128 (stores were fine) or critic_one surfaces in
// top-5 with its own counters.

#define BB 128
#define NN 64
#define OBSD 128
#define ACTD 16
#define DD 144
#define DKD 128
#define RS 168    // bf16 row stride for s_oa / s_W
#define RSQ 136   // bf16 row stride for s_Q / s_K

typedef float f32x4 __attribute__((ext_vector_type(4)));
typedef short bf16x8 __attribute__((ext_vector_type(8)));

__device__ __forceinline__ unsigned short bf1(float x) {
  unsigned u = __float_as_uint(x);
  return (unsigned short)((u + 0x7fffu + ((u >> 16) & 1u)) >> 16);
}
__device__ __forceinline__ unsigned int pack_bf2(float x, float y) {
  return (unsigned)bf1(x) | ((unsigned)bf1(y) << 16);
}
__device__ __forceinline__ float bf2f(unsigned short s) {
  return __uint_as_float(((unsigned)s) << 16);
}

// grid 512: b = bid>>2, i0 = (bid&3)*16. 512 threads (8 waves). ~94 KB LDS.
__global__ __launch_bounds__(512, 1) void critic_one(
    const float* __restrict__ obs, const float* __restrict__ pol,
    const float* __restrict__ act,
    const float* __restrict__ Wk, const float* __restrict__ Wq,
    const float* __restrict__ Wv, const float* __restrict__ Wenc,
    const float* __restrict__ Wfin, float* __restrict__ out)
{
  __shared__ __align__(16) unsigned short s_oa[NN * RS];    // 21504 B
  __shared__ __align__(16) unsigned short s_W[DKD * RS];    // 43008 B (Wq, then Wk)
  __shared__ __align__(16) unsigned short s_Q[NN * RSQ];    // 17408 B
  __shared__ __align__(16) unsigned short s_K[16 * RSQ];    // 4352 B
  __shared__ __align__(16) float s_w[16 * 68];              // 4352 B
  __shared__ unsigned short s_dpa[NN * ACTD];               // 2048 B
  __shared__ float s_u[DD];
  __shared__ float s_g[OBSD];
  __shared__ float s_vas[NN], s_dv[NN], s_ve[16], s_sv[16];

  const int tid = threadIdx.x;
  const int b = blockIdx.x >> 2;
  const int i0 = (blockIdx.x & 3) * 16;
  const int wv = tid >> 6, lane = tid & 63;
  const int m = lane & 15, q = lane >> 4;

  // ================= P0: stage oa, dpa, Wq; compute u,g =================
  {
    const float4* obs4 = (const float4*)(obs + (size_t)b * NN * OBSD);
    for (int idx = tid; idx < 2048; idx += 512) {           // 64 rows x 32 f4
      float4 v = obs4[idx];
      int row = idx >> 5, c4 = (idx & 31) * 4;
      *(uint2*)&s_oa[row * RS + c4] = make_uint2(pack_bf2(v.x, v.y), pack_bf2(v.z, v.w));
    }
    if (tid < 256) {                                        // act/pol: 64 rows x 4 f4
      const float4* act4 = (const float4*)(act + (size_t)b * NN * ACTD);
      const float4* pol4 = (const float4*)(pol + (size_t)b * NN * ACTD);
      float4 a = act4[tid], pp = pol4[tid];
      int row = tid >> 2, t0 = (tid & 3) * 4;
      *(uint2*)&s_oa[row * RS + OBSD + t0] = make_uint2(pack_bf2(a.x, a.y), pack_bf2(a.z, a.w));
      *(uint2*)&s_dpa[row * ACTD + t0] =
          make_uint2(pack_bf2(pp.x - a.x, pp.y - a.y), pack_bf2(pp.z - a.z, pp.w - a.w));
    } else if (tid < 512) {                                 // zero-pad oa cols 144..159
      int idx = tid - 256;
      int row = idx >> 2, c4 = DD + (idx & 3) * 4;
      *(uint2*)&s_oa[row * RS + c4] = make_uint2(0u, 0u);
    }
    const float4* W4 = (const float4*)Wq;                   // 128 rows x 36 f4
    for (int idx = tid; idx < 4608; idx += 512) {
      int row = idx / 36, g4 = idx - row * 36;
      float4 v = W4[idx];
      *(uint2*)&s_W[row * RS + g4 * 4] = make_uint2(pack_bf2(v.x, v.y), pack_bf2(v.z, v.w));
    }
    for (int idx = tid; idx < 512; idx += 512) {            // zero-pad W cols 144..159
      int row = idx >> 2, c4 = DD + (idx & 3) * 4;
      *(uint2*)&s_W[row * RS + c4] = make_uint2(0u, 0u);
    }
    // u[t] (t<144), g[d] (144<=t<272): coalesced f32, 8-way ILP
    if (tid < DD) {
      float a0=0.f,a1=0.f,a2=0.f,a3=0.f,a4=0.f,a5=0.f,a6=0.f,a7=0.f;
      for (int c = 0; c < DKD; c += 8) {
        a0 += Wv[(c+0)*DD + tid] * Wfin[OBSD + c + 0];
        a1 += Wv[(c+1)*DD + tid] * Wfin[OBSD + c + 1];
        a2 += Wv[(c+2)*DD + tid] * Wfin[OBSD + c + 2];
        a3 += Wv[(c+3)*DD + tid] * Wfin[OBSD + c + 3];
        a4 += Wv[(c+4)*DD + tid] * Wfin[OBSD + c + 4];
        a5 += Wv[(c+5)*DD + tid] * Wfin[OBSD + c + 5];
        a6 += Wv[(c+6)*DD + tid] * Wfin[OBSD + c + 6];
        a7 += Wv[(c+7)*DD + tid] * Wfin[OBSD + c + 7];
      }
      s_u[tid] = ((a0+a1)+(a2+a3)) + ((a4+a5)+(a6+a7));
    } else if (tid < DD + OBSD) {
      const int d = tid - DD;
      float a0=0.f,a1=0.f,a2=0.f,a3=0.f,a4=0.f,a5=0.f,a6=0.f,a7=0.f;
      for (int c = 0; c < 128; c += 8) {
        a0 += Wenc[(c+0)*OBSD + d] * Wfin[c + 0];
        a1 += Wenc[(c+1)*OBSD + d] * Wfin[c + 1];
        a2 += Wenc[(c+2)*OBSD + d] * Wfin[c + 2];
        a3 += Wenc[(c+3)*OBSD + d] * Wfin[c + 3];
        a4 += Wenc[(c+4)*OBSD + d] * Wfin[c + 4];
        a5 += Wenc[(c+5)*OBSD + d] * Wfin[c + 5];
        a6 += Wenc[(c+6)*OBSD + d] * Wfin[c + 6];
        a7 += Wenc[(c+7)*OBSD + d] * Wfin[c + 7];
      }
      s_g[d] = ((a0+a1)+(a2+a3)) + ((a4+a5)+(a6+a7));
    }
  }
  __syncthreads();

  // ====== P1: Q = oa @ Wq^T (full 64 rows). wave: jt = wv&3, ntiles (wv>>2)*4..+3
  {
    const int jt = wv & 3, n0 = (wv >> 2) * 4;
    f32x4 acc[4];
    #pragma unroll
    for (int t = 0; t < 4; ++t) acc[t] = (f32x4){0.f, 0.f, 0.f, 0.f};
    #pragma unroll
    for (int ks = 0; ks < 5; ++ks) {
      const int koff = ks * 32 + q * 8;
      bf16x8 a = *(const bf16x8*)&s_oa[(jt * 16 + m) * RS + koff];
      #pragma unroll
      for (int t = 0; t < 4; ++t) {
        bf16x8 bb = *(const bf16x8*)&s_W[((n0 + t) * 16 + m) * RS + koff];
        acc[t] = __builtin_amdgcn_mfma_f32_16x16x32_bf16(a, bb, acc[t], 0, 0, 0);
      }
    }
    #pragma unroll
    for (int t = 0; t < 4; ++t)
      #pragma unroll
      for (int r = 0; r < 4; ++r)
        s_Q[(jt * 16 + q * 4 + r) * RSQ + (n0 + t) * 16 + m] = bf1(acc[t][r]);
  }
  __syncthreads();                       // Wq reads done -> safe to overwrite s_W

  // ====== P2: re-stage s_W <- Wk (cols 0..143; pad stays zero)
  {
    const float4* W4 = (const float4*)Wk;
    for (int idx = tid; idx < 4608; idx += 512) {
      int row = idx / 36, g4 = idx - row * 36;
      float4 v = W4[idx];
      *(uint2*)&s_W[row * RS + g4 * 4] = make_uint2(pack_bf2(v.x, v.y), pack_bf2(v.z, v.w));
    }
  }
  __syncthreads();

  // ====== P3: K16 = oa[i0..i0+15] @ Wk^T. wave wv -> ntile wv
  {
    f32x4 acc = (f32x4){0.f, 0.f, 0.f, 0.f};
    #pragma unroll
    for (int ks = 0; ks < 5; ++ks) {
      const int koff = ks * 32 + q * 8;
      bf16x8 a = *(const bf16x8*)&s_oa[(i0 + m) * RS + koff];
      bf16x8 bb = *(const bf16x8*)&s_W[(wv * 16 + m) * RS + koff];
      acc = __builtin_amdgcn_mfma_f32_16x16x32_bf16(a, bb, acc, 0, 0, 0);
    }
    #pragma unroll
    for (int r = 0; r < 4; ++r)
      s_K[(q * 4 + r) * RSQ + wv * 16 + m] = bf1(acc[r]);
  }
  __syncthreads();

  // ====== P4: scores (waves 0-3) || vas/dv/ve (waves 4-6)
  if (wv < 4) {                          // jtile = wv; K-dim 128 = 4 ksteps
    f32x4 sc = (f32x4){0.f, 0.f, 0.f, 0.f};
    #pragma unroll
    for (int ks = 0; ks < 4; ++ks) {
      const int koff = ks * 32 + q * 8;
      bf16x8 a = *(const bf16x8*)&s_K[m * RSQ + koff];
      bf16x8 bb = *(const bf16x8*)&s_Q[(wv * 16 + m) * RSQ + koff];
      sc = __builtin_amdgcn_mfma_f32_16x16x32_bf16(a, bb, sc, 0, 0, 0);
    }
    const float kk = 0.08838834764831845f;   // 1/sqrt(128)
    #pragma unroll
    for (int r = 0; r < 4; ++r)
      s_w[(q * 4 + r) * 68 + wv * 16 + m] = 1.0f / (1.0f + __expf(-sc[r] * kk));
  } else if (wv == 4) {                  // dv[m] = dpa[m].u[128:144]
    float a = 0.f;
    #pragma unroll
    for (int t = 0; t < ACTD; ++t) a += bf2f(s_dpa[lane * ACTD + t]) * s_u[OBSD + t];
    s_dv[lane] = a;
  } else if (wv == 5) {                  // vas[j] = oa[j].u
    float a = 0.f;
    for (int d = 0; d < DD; ++d) a += bf2f(s_oa[lane * RS + d]) * s_u[d];
    s_vas[lane] = a;
  } else if (wv == 6 && lane < 16) {     // ve for this block's 16 rows
    float a = 0.f;
    for (int d = 0; d < OBSD; ++d) a += bf2f(s_oa[(i0 + lane) * RS + d]) * s_g[d];
    s_ve[lane] = a;
  }
  __syncthreads();

  if (tid < 16) {                        // sv[i] = sum_j w[i,j] vas[j]
    float a = 0.f;
    for (int j = 0; j < NN; ++j) a += s_w[tid * 68 + j] * s_vas[j];
    s_sv[tid] = a;
  }
  __syncthreads();

  // ====== P5: value rows
  if (tid < 256) {
    const int r = tid >> 4, m4 = (tid & 15) * 4;
    float4 v;
    v.x = s_ve[r] + (s_sv[r] + s_w[r * 68 + m4 + 0] * s_dv[m4 + 0]) * (1.0f / 64.0f);
    v.y = s_ve[r] + (s_sv[r] + s_w[r * 68 + m4 + 1] * s_dv[m4 + 1]) * (1.0f / 64.0f);
    v.z = s_ve[r] + (s_sv[r] + s_w[r * 68 + m4 + 2] * s_dv[m4 + 2]) * (1.0f / 64.0f);
    v.w = s_ve[r] + (s_sv[r] + s_w[r * 68 + m4 + 3] * s_dv[m4 + 3]) * (1.0f / 64.0f);
    *(float4*)(out + ((size_t)(b * 64 + i0 + r) * 64 + m4)) = v;
  }

  // ====== P6: broadcast. Hoist ALL 16 LDS reads, then a pure 32-store burst.
  float4 wr[16];
  #pragma unroll
  for (int r = 0; r < 16; ++r)
    wr[r] = *(const float4*)&s_w[r * 68 + (tid & 15) * 4];
  float* w5 = out + (size_t)BB * NN * NN;
  #pragma unroll
  for (int r = 0; r < 16; ++r) {
    float4* p4 = (float4*)(w5 + ((size_t)(b * 64 + i0 + r) << 12));
    p4[tid]       = wr[r];
    p4[tid + 512] = wr[r];
  }
}

extern "C" void kernel_launch(void* const* d_in, const int* in_sizes, int n_in,
                              void* d_out, int out_size, void* d_ws, size_t ws_size,
                              hipStream_t stream) {
  (void)in_sizes; (void)n_in; (void)out_size; (void)d_ws; (void)ws_size;
  const float* obs  = (const float*)d_in[0];
  const float* pol  = (const float*)d_in[1];
  const float* act  = (const float*)d_in[2];
  const float* Wk   = (const float*)d_in[3];
  const float* Wq   = (const float*)d_in[4];
  const float* Wv   = (const float*)d_in[5];
  const float* Wenc = (const float*)d_in[6];
  const float* Wfin = (const float*)d_in[7];
  float* out = (float*)d_out;
  hipLaunchKernelGGL(critic_one, dim3(BB * 4), dim3(512), 0, stream,
                     obs, pol, act, Wk, Wq, Wv, Wenc, Wfin, out);
}